// Round 1
// baseline (138.473 us; speedup 1.0000x reference)
//
#include <hip/hip_runtime.h>
#include <stdint.h>

#define N 8192
#define Dq 64
#define SPLITS 8
#define CPS (N / SPLITS)   // 1024 candidates per split
#define MARGIN 0.5f

typedef __attribute__((ext_vector_type(8))) short short8;   // 8 bf16 (4 VGPRs)
typedef __attribute__((ext_vector_type(4))) float floatx4;  // MFMA accumulator

__device__ __forceinline__ unsigned short f2bf(float f) {
  unsigned u = __float_as_uint(f);
  u += 0x7FFF + ((u >> 16) & 1);   // round-to-nearest-even
  return (unsigned short)(u >> 16);
}

// Kernel 1: fp32 -> bf16 convert, row squared norms, class copy, zero output.
__global__ __launch_bounds__(256) void prep_kernel(
    const float* __restrict__ emb, const int* __restrict__ tgt,
    unsigned short* __restrict__ embB, float* __restrict__ sq,
    int* __restrict__ cls, float* __restrict__ out) {
  int i = blockIdx.x * blockDim.x + threadIdx.x;
  if (i >= N) return;
  const float4* x = reinterpret_cast<const float4*>(emb + i * Dq);
  ushort4* yb = reinterpret_cast<ushort4*>(embB + i * Dq);
  float s = 0.f;
  #pragma unroll
  for (int k = 0; k < Dq / 4; ++k) {
    float4 v = x[k];
    s = fmaf(v.x, v.x, s); s = fmaf(v.y, v.y, s);
    s = fmaf(v.z, v.z, s); s = fmaf(v.w, v.w, s);
    ushort4 b;
    b.x = f2bf(v.x); b.y = f2bf(v.y); b.z = f2bf(v.z); b.w = f2bf(v.w);
    yb[k] = b;
  }
  sq[i] = s;
  cls[i] = tgt[i];
  if (i == 0) out[0] = 0.f;
}

// Kernel 2: batch-hard mining. Each wave owns 16 anchor rows (A-frag pinned in
// registers), streams candidate tiles of 16 from L2, MFMA dot-products, fused
// argmax(same)/argmin(diff) epilogue. Candidate dim split over blockIdx.y.
__global__ __launch_bounds__(256) void mine_kernel(
    const unsigned short* __restrict__ embB,
    const float* __restrict__ sq, const int* __restrict__ cls,
    float* __restrict__ pmaxv, int* __restrict__ pmaxi,
    float* __restrict__ pminv, int* __restrict__ pmini) {
  const int lane = threadIdx.x & 63;
  const int wave = threadIdx.x >> 6;
  const int lo = lane & 15;
  const int quad = lane >> 4;
  const int rowBase = blockIdx.x * 64 + wave * 16;
  const int split = blockIdx.y;
  const int c0 = split * CPS;

  // A fragments: A[m=lane&15][k=quad*8+j], two K=32 halves. 16B contiguous.
  const short8* ea =
      reinterpret_cast<const short8*>(embB + (rowBase + lo) * Dq + quad * 8);
  short8 a0 = ea[0];   // k in [0,32)
  short8 a1 = ea[4];   // k in [32,64)  (+32 shorts = +4 short8)

  // C/D layout: col = lane&15, row = quad*4 + reg. Per-row norms & classes.
  float sqi[4]; int ci[4];
  #pragma unroll
  for (int r = 0; r < 4; ++r) {
    int row = rowBase + quad * 4 + r;
    sqi[r] = sq[row];
    ci[r] = cls[row];
  }

  float maxv[4], minv[4]; int maxi[4], mini[4];
  #pragma unroll
  for (int r = 0; r < 4; ++r) {
    maxv[r] = -INFINITY; minv[r] = INFINITY; maxi[r] = 0; mini[r] = 0;
  }

  for (int ct = 0; ct < CPS / 16; ++ct) {
    const int cb = c0 + ct * 16;
    // B fragment: B[k=quad*8+j][n=lane&15] = x_{cb+n}[k] — same gather as A.
    const short8* eb =
        reinterpret_cast<const short8*>(embB + (cb + lo) * Dq + quad * 8);
    short8 b0 = eb[0];
    short8 b1 = eb[4];
    float sqj = sq[cb + lo];
    int cj = cls[cb + lo];
    floatx4 acc = {0.f, 0.f, 0.f, 0.f};
    acc = __builtin_amdgcn_mfma_f32_16x16x32_bf16(a0, b0, acc, 0, 0, 0);
    acc = __builtin_amdgcn_mfma_f32_16x16x32_bf16(a1, b1, acc, 0, 0, 0);
    const int jidx = cb + lo;
    #pragma unroll
    for (int r = 0; r < 4; ++r) {
      float d = fmaf(acc[r], -2.0f, sqi[r]) + sqj;
      d = fmaxf(d, 0.f);
      bool same = (ci[r] == cj);
      bool bp = same && (d > maxv[r]);
      maxv[r] = bp ? d : maxv[r];
      maxi[r] = bp ? jidx : maxi[r];
      bool bn = (!same) && (d < minv[r]);
      minv[r] = bn ? d : minv[r];
      mini[r] = bn ? jidx : mini[r];
    }
  }

  // Reduce across the 16 lanes of each quad (they hold different columns of
  // the same 4 rows). Tie-break: smaller candidate index wins (jnp argmax/min).
  #pragma unroll
  for (int off = 1; off < 16; off <<= 1) {
    #pragma unroll
    for (int r = 0; r < 4; ++r) {
      float ov = __shfl_xor(maxv[r], off);
      int oi = __shfl_xor(maxi[r], off);
      if (ov > maxv[r] || (ov == maxv[r] && oi < maxi[r])) { maxv[r] = ov; maxi[r] = oi; }
      ov = __shfl_xor(minv[r], off);
      oi = __shfl_xor(mini[r], off);
      if (ov < minv[r] || (ov == minv[r] && oi < mini[r])) { minv[r] = ov; mini[r] = oi; }
    }
  }

  if (lo == 0) {
    #pragma unroll
    for (int r = 0; r < 4; ++r) {
      int row = rowBase + quad * 4 + r;
      int o = split * N + row;
      pmaxv[o] = maxv[r]; pmaxi[o] = maxi[r];
      pminv[o] = minv[r]; pmini[o] = mini[r];
    }
  }
}

// Kernel 3: combine splits (index-ordered, strict compare = first-index ties),
// recompute ap/an in fp32 from ORIGINAL embeddings (matches reference), mean.
__global__ __launch_bounds__(256) void finalize_kernel(
    const float* __restrict__ emb,
    const float* __restrict__ pmaxv, const int* __restrict__ pmaxi,
    const float* __restrict__ pminv, const int* __restrict__ pmini,
    float* __restrict__ out) {
  int i = blockIdx.x * blockDim.x + threadIdx.x;
  float mv = -INFINITY; int mi = 0;
  float nv = INFINITY;  int ni = 0;
  #pragma unroll
  for (int s = 0; s < SPLITS; ++s) {
    float v = pmaxv[s * N + i]; int ix = pmaxi[s * N + i];
    if (v > mv || (v == mv && ix < mi)) { mv = v; mi = ix; }
    v = pminv[s * N + i]; ix = pmini[s * N + i];
    if (v < nv || (v == nv && ix < ni)) { nv = v; ni = ix; }
  }
  const float4* xi = reinterpret_cast<const float4*>(emb + i * Dq);
  const float4* xp = reinterpret_cast<const float4*>(emb + mi * Dq);
  const float4* xn = reinterpret_cast<const float4*>(emb + ni * Dq);
  float ap = 0.f, an = 0.f;
  #pragma unroll
  for (int k = 0; k < Dq / 4; ++k) {
    float4 a = xi[k], p = xp[k], q = xn[k];
    float dx = a.x - p.x, dy = a.y - p.y, dz = a.z - p.z, dw = a.w - p.w;
    ap += dx * dx + dy * dy + dz * dz + dw * dw;
    dx = a.x - q.x; dy = a.y - q.y; dz = a.z - q.z; dw = a.w - q.w;
    an += dx * dx + dy * dy + dz * dz + dw * dw;
  }
  float loss = fmaxf(ap - an + MARGIN, 0.f);
  #pragma unroll
  for (int off = 32; off > 0; off >>= 1) loss += __shfl_down(loss, off);
  __shared__ float wsum[4];
  if ((threadIdx.x & 63) == 0) wsum[threadIdx.x >> 6] = loss;
  __syncthreads();
  if (threadIdx.x == 0)
    atomicAdd(out, (wsum[0] + wsum[1] + wsum[2] + wsum[3]) * (1.0f / (float)N));
}

extern "C" void kernel_launch(void* const* d_in, const int* in_sizes, int n_in,
                              void* d_out, int out_size, void* d_ws, size_t ws_size,
                              hipStream_t stream) {
  const float* emb = (const float*)d_in[0];
  const int* tgt = (const int*)d_in[1];
  float* out = (float*)d_out;

  char* ws = (char*)d_ws;
  unsigned short* embB = (unsigned short*)ws;                 // 1 MB
  float* sq = (float*)(ws + (size_t)N * Dq * 2);              // 32 KB
  int* cls = (int*)(ws + (size_t)N * Dq * 2 + (size_t)N * 4); // 32 KB
  char* p = ws + (size_t)N * Dq * 2 + (size_t)N * 8;
  float* pmaxv = (float*)p; p += (size_t)SPLITS * N * 4;
  int*   pmaxi = (int*)p;   p += (size_t)SPLITS * N * 4;
  float* pminv = (float*)p; p += (size_t)SPLITS * N * 4;
  int*   pmini = (int*)p;

  prep_kernel<<<N / 256, 256, 0, stream>>>(emb, tgt, embB, sq, cls, out);
  mine_kernel<<<dim3(N / 64, SPLITS), 256, 0, stream>>>(embB, sq, cls,
                                                        pmaxv, pmaxi, pminv, pmini);
  finalize_kernel<<<N / 256, 256, 0, stream>>>(emb, pmaxv, pmaxi, pminv, pmini, out);
}

// Round 2
// 100.394 us; speedup vs baseline: 1.3793x; 1.3793x over previous
//
#include <hip/hip_runtime.h>
#include <stdint.h>

#define N 8192
#define Dq 64
#define SPLITS 12          // 256 cand-tiles split ~21-22 tiles each; 64*12=768 blocks = 3/CU
#define MARGIN 0.5f

typedef __attribute__((ext_vector_type(8))) short short8;     // 8 bf16 (4 VGPRs)
typedef __attribute__((ext_vector_type(16))) float floatx16;  // 32x32 MFMA accumulator

__device__ __forceinline__ unsigned short f2bf(float f) {
  unsigned u = __float_as_uint(f);
  u += 0x7FFF + ((u >> 16) & 1);   // round-to-nearest-even
  return (unsigned short)(u >> 16);
}

// Kernel 1: fp32 -> bf16 convert + row squared norms. One thread per float4
// (16 threads per row), butterfly-reduce the norm across the 16 lanes.
__global__ __launch_bounds__(256) void prep_kernel(
    const float* __restrict__ emb,
    unsigned short* __restrict__ embB, float* __restrict__ sq,
    float* __restrict__ out) {
  int tid = blockIdx.x * 256 + threadIdx.x;     // N*16 threads
  int row = tid >> 4;
  int c = tid & 15;
  float4 v = reinterpret_cast<const float4*>(emb)[row * 16 + c];
  float s = v.x * v.x + v.y * v.y + v.z * v.z + v.w * v.w;
  #pragma unroll
  for (int off = 1; off < 16; off <<= 1) s += __shfl_xor(s, off);
  if (c == 0) sq[row] = s;
  ushort4 b;
  b.x = f2bf(v.x); b.y = f2bf(v.y); b.z = f2bf(v.z); b.w = f2bf(v.w);
  reinterpret_cast<ushort4*>(embB)[row * 16 + c] = b;
  if (tid == 0) out[0] = 0.f;
}

// Kernel 2: batch-hard mining with 32x32x16 MFMA. Each wave pins 32 anchor
// rows (4 A-frags) and streams 32-candidate tiles; per tile 4 MFMAs + a
// packed-u32-key argmax/argmin epilogue over 16 acc regs.
// Key = (bits(d) & ~0x1FFF) | idx13. d>=0 so float bits are u32-monotone.
// argmax uses idx = 8191-j (ties -> smaller j); argmin uses idx = j.
__global__ __launch_bounds__(256, 3) void mine_kernel(
    const unsigned short* __restrict__ embB,
    const float* __restrict__ sq, const int* __restrict__ cls,
    unsigned* __restrict__ pmax, unsigned* __restrict__ pmin) {
  const int lane = threadIdx.x & 63;
  const int wave = threadIdx.x >> 6;
  const int lo = lane & 31;
  const int half = lane >> 5;
  const int rowBase = (blockIdx.x * 4 + wave) * 32;
  const int split = blockIdx.y;
  const int t0 = (256 * split) / SPLITS;
  const int t1 = (256 * (split + 1)) / SPLITS;

  // A frag h: A[m=lo][k = h*16 + half*8 + j], 16B contiguous per lane.
  const short8* ea =
      reinterpret_cast<const short8*>(embB + (size_t)(rowBase + lo) * Dq + half * 8);
  short8 a0 = ea[0], a1 = ea[2], a2 = ea[4], a3 = ea[6];

  // C/D layout (m74/m101): col = lane&31, row = (reg&3) + 8*(reg>>2) + 4*half.
  float sqi[16]; int ci[16];
  #pragma unroll
  for (int r = 0; r < 16; ++r) {
    int row = rowBase + (r & 3) + 8 * (r >> 2) + 4 * half;
    sqi[r] = sq[row]; ci[r] = cls[row];
  }

  unsigned maxk[16], mink[16];
  #pragma unroll
  for (int r = 0; r < 16; ++r) { maxk[r] = 0u; mink[r] = 0xFFFFFFFFu; }

  for (int t = t0; t < t1; ++t) {
    const int cb = t * 32;
    const short8* eb =
        reinterpret_cast<const short8*>(embB + (size_t)(cb + lo) * Dq + half * 8);
    short8 b0 = eb[0], b1 = eb[2], b2 = eb[4], b3 = eb[6];
    float sqj = sq[cb + lo];
    int cj = cls[cb + lo];

    floatx16 acc;
    #pragma unroll
    for (int i = 0; i < 16; ++i) acc[i] = 0.f;
    acc = __builtin_amdgcn_mfma_f32_32x32x16_bf16(a0, b0, acc, 0, 0, 0);
    acc = __builtin_amdgcn_mfma_f32_32x32x16_bf16(a1, b1, acc, 0, 0, 0);
    acc = __builtin_amdgcn_mfma_f32_32x32x16_bf16(a2, b2, acc, 0, 0, 0);
    acc = __builtin_amdgcn_mfma_f32_32x32x16_bf16(a3, b3, acc, 0, 0, 0);

    const unsigned j = cb + lo;
    const unsigned jinv = 8191u - j;
    #pragma unroll
    for (int r = 0; r < 16; ++r) {
      float d = fmaf(acc[r], -2.0f, sqi[r]) + sqj;
      d = fmaxf(d, 0.0f);
      unsigned kb = __float_as_uint(d) & 0xFFFFE000u;
      bool same = (ci[r] == cj);
      unsigned kp = same ? (kb | jinv) : 0u;
      unsigned kn = same ? 0xFFFFFFFFu : (kb | j);
      maxk[r] = maxk[r] > kp ? maxk[r] : kp;
      mink[r] = mink[r] < kn ? mink[r] : kn;
    }
  }

  // Column reduction: each half-wave (32 lanes) holds all 32 cols of its rows.
  #pragma unroll
  for (int off = 1; off < 32; off <<= 1) {
    #pragma unroll
    for (int r = 0; r < 16; ++r) {
      unsigned om = (unsigned)__shfl_xor((int)maxk[r], off);
      maxk[r] = maxk[r] > om ? maxk[r] : om;
      unsigned on = (unsigned)__shfl_xor((int)mink[r], off);
      mink[r] = mink[r] < on ? mink[r] : on;
    }
  }

  if (lo == 0) {
    #pragma unroll
    for (int r = 0; r < 16; ++r) {
      int row = rowBase + (r & 3) + 8 * (r >> 2) + 4 * half;
      pmax[split * N + row] = maxk[r];
      pmin[split * N + row] = mink[r];
    }
  }
}

// Kernel 3: combine split keys (u32 max/min; index embedded -> global
// tie-break is automatic), decode indices, recompute ap/an in fp32 from the
// ORIGINAL embeddings (matches reference), relu+margin, mean.
// 4 lanes per anchor, each handles 16 of the 64 dims.
__global__ __launch_bounds__(256) void finalize_kernel(
    const float* __restrict__ emb,
    const unsigned* __restrict__ pmax, const unsigned* __restrict__ pmin,
    float* __restrict__ out) {
  int tid = blockIdx.x * 256 + threadIdx.x;   // N*4 threads
  int anchor = tid >> 2;
  int part = tid & 3;
  unsigned Kp = 0u, Kn = 0xFFFFFFFFu;
  #pragma unroll
  for (int s = 0; s < SPLITS; ++s) {
    unsigned vp = pmax[s * N + anchor];
    Kp = Kp > vp ? Kp : vp;
    unsigned vn = pmin[s * N + anchor];
    Kn = Kn < vn ? Kn : vn;
  }
  int jp = 8191 - (int)(Kp & 8191u);
  int jn = (int)(Kn & 8191u);

  const float4* xi = reinterpret_cast<const float4*>(emb + (size_t)anchor * Dq) + part * 4;
  const float4* xp = reinterpret_cast<const float4*>(emb + (size_t)jp * Dq) + part * 4;
  const float4* xn = reinterpret_cast<const float4*>(emb + (size_t)jn * Dq) + part * 4;
  float ap = 0.f, an = 0.f;
  #pragma unroll
  for (int k = 0; k < 4; ++k) {
    float4 a = xi[k], p = xp[k], q = xn[k];
    float dx = a.x - p.x, dy = a.y - p.y, dz = a.z - p.z, dw = a.w - p.w;
    ap += dx * dx + dy * dy + dz * dz + dw * dw;
    dx = a.x - q.x; dy = a.y - q.y; dz = a.z - q.z; dw = a.w - q.w;
    an += dx * dx + dy * dy + dz * dz + dw * dw;
  }
  // sum across the 4 lanes of this anchor
  #pragma unroll
  for (int off = 1; off < 4; off <<= 1) {
    ap += __shfl_xor(ap, off);
    an += __shfl_xor(an, off);
  }
  float loss = (part == 0) ? fmaxf(ap - an + MARGIN, 0.f) : 0.f;
  #pragma unroll
  for (int off = 4; off < 64; off <<= 1) loss += __shfl_xor(loss, off);
  __shared__ float wsum[4];
  if ((threadIdx.x & 63) == 0) wsum[threadIdx.x >> 6] = loss;
  __syncthreads();
  if (threadIdx.x == 0)
    atomicAdd(out, (wsum[0] + wsum[1] + wsum[2] + wsum[3]) * (1.0f / (float)N));
}

extern "C" void kernel_launch(void* const* d_in, const int* in_sizes, int n_in,
                              void* d_out, int out_size, void* d_ws, size_t ws_size,
                              hipStream_t stream) {
  const float* emb = (const float*)d_in[0];
  const int* tgt = (const int*)d_in[1];   // int32 on device (verified round 1)
  float* out = (float*)d_out;

  char* ws = (char*)d_ws;
  unsigned short* embB = (unsigned short*)ws;                 // 1 MB
  float* sq = (float*)(ws + (size_t)N * Dq * 2);              // 32 KB
  char* p = ws + (size_t)N * Dq * 2 + (size_t)N * 4;
  unsigned* pmax = (unsigned*)p; p += (size_t)SPLITS * N * 4; // 384 KB
  unsigned* pmin = (unsigned*)p;                              // 384 KB

  prep_kernel<<<N * 16 / 256, 256, 0, stream>>>(emb, embB, sq, out);
  mine_kernel<<<dim3(N / 128, SPLITS), 256, 0, stream>>>(embB, sq, tgt, pmax, pmin);
  finalize_kernel<<<N * 4 / 256, 256, 0, stream>>>(emb, pmax, pmin, out);
}

// Round 3
// 99.629 us; speedup vs baseline: 1.3899x; 1.0077x over previous
//
#include <hip/hip_runtime.h>
#include <stdint.h>

#define N 8192
#define Dq 64
#define SPLITS 16          // 256 cand-tiles / 16 = 16 tiles per wave, 1024 blocks = 4/CU
#define MARGIN 0.5f

typedef __attribute__((ext_vector_type(8))) short short8;     // 8 bf16 (4 VGPRs)
typedef __attribute__((ext_vector_type(16))) float floatx16;  // 32x32 MFMA accumulator

__device__ __forceinline__ unsigned short f2bf(float f) {
  unsigned u = __float_as_uint(f);
  u += 0x7FFF + ((u >> 16) & 1);   // round-to-nearest-even (valid for any sign)
  return (unsigned short)(u >> 16);
}

// Kernel 1: fp32 -> bf16 convert, encode aug-norm bf16(-(0.5*sq+2)), init
// atomic-key arrays and output. One thread per float4 (16 threads/row).
__global__ __launch_bounds__(256) void prep_kernel(
    const float* __restrict__ emb,
    unsigned short* __restrict__ embB, unsigned short* __restrict__ sqb,
    unsigned* __restrict__ pmax, unsigned* __restrict__ pmin,
    float* __restrict__ out) {
  int tid = blockIdx.x * 256 + threadIdx.x;     // N*16 threads
  int row = tid >> 4;
  int c = tid & 15;
  float4 v = reinterpret_cast<const float4*>(emb)[row * 16 + c];
  float s = v.x * v.x + v.y * v.y + v.z * v.z + v.w * v.w;
  #pragma unroll
  for (int off = 1; off < 16; off <<= 1) s += __shfl_xor(s, off);
  if (c == 0) sqb[row] = f2bf(-(0.5f * s + 2.0f));
  ushort4 b;
  b.x = f2bf(v.x); b.y = f2bf(v.y); b.z = f2bf(v.z); b.w = f2bf(v.w);
  reinterpret_cast<ushort4*>(embB)[row * 16 + c] = b;
  if (tid < N) { pmax[tid] = 0u; pmin[tid] = 0xFFFFFFFFu; }
  if (tid == 0) out[0] = 0.f;
}

// Kernel 2: batch-hard mining, 32x32 tiles. acc = dot - 0.5(sq_i+sq_j) - 4 =
// -(d/2+4) < 0 via a 5th augmented MFMA; for all-negative floats the u32 bit
// pattern is monotone INCREASING in d, so keys = (bits(acc)&~0x1FFF)|idx13
// give argmax(d)=u32max, argmin(d)=u32min directly. Results combined globally
// with atomicMax/atomicMin (tie-break: jinv for max -> smaller j, j for min).
__global__ __launch_bounds__(256, 4) void mine_kernel(
    const unsigned short* __restrict__ embB,
    const unsigned short* __restrict__ sqb, const int* __restrict__ cls,
    unsigned* __restrict__ pmax, unsigned* __restrict__ pmin) {
  const int lane = threadIdx.x & 63;
  const int wave = threadIdx.x >> 6;
  const int lo = lane & 31;
  const int half = lane >> 5;
  const int rowBase = (blockIdx.x * 4 + wave) * 32;
  const int tBase = blockIdx.y * (256 / SPLITS);

  // A frag h: A[m=lo][k = h*16 + half*8 + j], 16B contiguous per lane.
  const short8* ea =
      reinterpret_cast<const short8*>(embB + (size_t)(rowBase + lo) * Dq + half * 8);
  short8 a0 = ea[0], a1 = ea[2], a2 = ea[4], a3 = ea[6];
  // Aug A frag: A'[m][0]=1.0, A'[m][1]=-(0.5*sq_m+2) (pre-encoded in sqb).
  unsigned short sqm = sqb[rowBase + lo];
  const short one = (short)0x3F80;   // bf16 1.0
  short8 a4 = {(short)(half == 0 ? one : 0),
               (short)(half == 0 ? (short)sqm : 0), 0, 0, 0, 0, 0, 0};

  // C/D layout: col = lane&31, row = (reg&3) + 8*(reg>>2) + 4*half.
  int ci[16];
  #pragma unroll
  for (int r = 0; r < 16; ++r)
    ci[r] = cls[rowBase + (r & 3) + 8 * (r >> 2) + 4 * half];

  unsigned maxk[16], mink[16];
  #pragma unroll
  for (int r = 0; r < 16; ++r) { maxk[r] = 0u; mink[r] = 0xFFFFFFFFu; }

  #pragma unroll 2
  for (int t = 0; t < 256 / SPLITS; ++t) {
    const int cb = (tBase + t) * 32;
    const short8* eb =
        reinterpret_cast<const short8*>(embB + (size_t)(cb + lo) * Dq + half * 8);
    short8 b0 = eb[0], b1 = eb[2], b2 = eb[4], b3 = eb[6];
    unsigned short sqn = sqb[cb + lo];
    int cj = cls[cb + lo];
    short8 b4 = {(short)(half == 0 ? (short)sqn : 0),
                 (short)(half == 0 ? one : 0), 0, 0, 0, 0, 0, 0};

    floatx16 acc;
    #pragma unroll
    for (int i = 0; i < 16; ++i) acc[i] = 0.f;
    acc = __builtin_amdgcn_mfma_f32_32x32x16_bf16(a0, b0, acc, 0, 0, 0);
    acc = __builtin_amdgcn_mfma_f32_32x32x16_bf16(a1, b1, acc, 0, 0, 0);
    acc = __builtin_amdgcn_mfma_f32_32x32x16_bf16(a2, b2, acc, 0, 0, 0);
    acc = __builtin_amdgcn_mfma_f32_32x32x16_bf16(a3, b3, acc, 0, 0, 0);
    acc = __builtin_amdgcn_mfma_f32_32x32x16_bf16(a4, b4, acc, 0, 0, 0);

    const unsigned j = cb + lo;
    const unsigned jinv = 8191u - j;
    #pragma unroll
    for (int r = 0; r < 16; ++r) {
      unsigned kb = __float_as_uint(acc[r]) & 0xFFFFE000u;
      bool same = (ci[r] == cj);
      unsigned kp = same ? (kb | jinv) : 0u;
      unsigned kn = same ? 0xFFFFFFFFu : (kb | j);
      maxk[r] = maxk[r] > kp ? maxk[r] : kp;
      mink[r] = mink[r] < kn ? mink[r] : kn;
    }
  }

  // Column reduction within each 32-lane half (xor masks 1..16 stay in-half).
  #pragma unroll
  for (int off = 1; off < 32; off <<= 1) {
    #pragma unroll
    for (int r = 0; r < 16; ++r) {
      unsigned om = (unsigned)__shfl_xor((int)maxk[r], off);
      maxk[r] = maxk[r] > om ? maxk[r] : om;
      unsigned on = (unsigned)__shfl_xor((int)mink[r], off);
      mink[r] = mink[r] < on ? mink[r] : on;
    }
  }

  if (lo == 0) {
    #pragma unroll
    for (int r = 0; r < 16; ++r) {
      int row = rowBase + (r & 3) + 8 * (r >> 2) + 4 * half;
      atomicMax(&pmax[row], maxk[r]);
      atomicMin(&pmin[row], mink[r]);
    }
  }
}

// Kernel 3: decode winning indices, recompute ap/an in fp32 from ORIGINAL
// embeddings (matches reference), relu+margin, mean. 4 lanes per anchor.
__global__ __launch_bounds__(256) void finalize_kernel(
    const float* __restrict__ emb,
    const unsigned* __restrict__ pmax, const unsigned* __restrict__ pmin,
    float* __restrict__ out) {
  int tid = blockIdx.x * 256 + threadIdx.x;   // N*4 threads
  int anchor = tid >> 2;
  int part = tid & 3;
  int jp = 8191 - (int)(pmax[anchor] & 8191u);
  int jn = (int)(pmin[anchor] & 8191u);

  const float4* xi = reinterpret_cast<const float4*>(emb + (size_t)anchor * Dq) + part * 4;
  const float4* xp = reinterpret_cast<const float4*>(emb + (size_t)jp * Dq) + part * 4;
  const float4* xn = reinterpret_cast<const float4*>(emb + (size_t)jn * Dq) + part * 4;
  float ap = 0.f, an = 0.f;
  #pragma unroll
  for (int k = 0; k < 4; ++k) {
    float4 a = xi[k], p = xp[k], q = xn[k];
    float dx = a.x - p.x, dy = a.y - p.y, dz = a.z - p.z, dw = a.w - p.w;
    ap += dx * dx + dy * dy + dz * dz + dw * dw;
    dx = a.x - q.x; dy = a.y - q.y; dz = a.z - q.z; dw = a.w - q.w;
    an += dx * dx + dy * dy + dz * dz + dw * dw;
  }
  #pragma unroll
  for (int off = 1; off < 4; off <<= 1) {
    ap += __shfl_xor(ap, off);
    an += __shfl_xor(an, off);
  }
  float loss = (part == 0) ? fmaxf(ap - an + MARGIN, 0.f) : 0.f;
  #pragma unroll
  for (int off = 4; off < 64; off <<= 1) loss += __shfl_xor(loss, off);
  __shared__ float wsum[4];
  if ((threadIdx.x & 63) == 0) wsum[threadIdx.x >> 6] = loss;
  __syncthreads();
  if (threadIdx.x == 0)
    atomicAdd(out, (wsum[0] + wsum[1] + wsum[2] + wsum[3]) * (1.0f / (float)N));
}

extern "C" void kernel_launch(void* const* d_in, const int* in_sizes, int n_in,
                              void* d_out, int out_size, void* d_ws, size_t ws_size,
                              hipStream_t stream) {
  const float* emb = (const float*)d_in[0];
  const int* tgt = (const int*)d_in[1];   // int32 on device (verified R1/R2)
  float* out = (float*)d_out;

  char* ws = (char*)d_ws;
  unsigned short* embB = (unsigned short*)ws;                    // 1 MB
  unsigned short* sqb = (unsigned short*)(ws + (size_t)N * Dq * 2); // 16 KB
  unsigned* pmax = (unsigned*)(ws + (size_t)N * Dq * 2 + N * 2);    // 32 KB
  unsigned* pmin = pmax + N;                                        // 32 KB

  prep_kernel<<<N * 16 / 256, 256, 0, stream>>>(emb, embB, sqb, pmax, pmin, out);
  mine_kernel<<<dim3(N / 128, SPLITS), 256, 0, stream>>>(embB, sqb, tgt, pmax, pmin);
  finalize_kernel<<<N * 4 / 256, 256, 0, stream>>>(emb, pmax, pmin, out);
}

// Round 4
// 90.931 us; speedup vs baseline: 1.5228x; 1.0957x over previous
//
#include <hip/hip_runtime.h>
#include <stdint.h>

#define N 8192
#define Dq 64
#define SPLITS 16          // 256 cand-tiles / 16 = 16 tiles per wave, 1024 blocks = 4/CU
#define MARGIN 0.5f

typedef __attribute__((ext_vector_type(8))) short short8;     // 8 bf16 (4 VGPRs)
typedef __attribute__((ext_vector_type(16))) float floatx16;  // 32x32 MFMA accumulator

__device__ __forceinline__ unsigned short f2bf(float f) {
  unsigned u = __float_as_uint(f);
  u += 0x7FFF + ((u >> 16) & 1);   // round-to-nearest-even
  return (unsigned short)(u >> 16);
}

// Kernel 1: fp32 -> bf16 convert into FRAGMENT-READY tiled layout + aug-norm
// encode + atomic-key init. Layout: embF[tile t][chunk c][lane l] (16B) where
// lane l gets row t*32+(l&31), shorts (l>>5)*8 + c*16 .. +7. Then a wave's
// fragment chunk c load is embF + t*2048 + c*512 + l*8 shorts — perfectly
// coalesced (consecutive lanes -> consecutive 16B).
// One thread per 8 floats (N*8 threads); norm butterfly over 8 lanes.
__global__ __launch_bounds__(256) void prep_kernel(
    const float* __restrict__ emb,
    unsigned short* __restrict__ embF, unsigned short* __restrict__ sqb,
    unsigned* __restrict__ pmax, unsigned* __restrict__ pmin,
    float* __restrict__ out) {
  int tid = blockIdx.x * 256 + threadIdx.x;     // N*8 threads
  int row = tid >> 3;
  int m = tid & 7;                               // chunk-of-8-shorts index
  const float4* src = reinterpret_cast<const float4*>(emb) + (size_t)row * 16 + m * 2;
  float4 v0 = src[0], v1 = src[1];
  float s = v0.x * v0.x + v0.y * v0.y + v0.z * v0.z + v0.w * v0.w
          + v1.x * v1.x + v1.y * v1.y + v1.z * v1.z + v1.w * v1.w;
  #pragma unroll
  for (int off = 1; off < 8; off <<= 1) s += __shfl_xor(s, off);
  if (m == 0) sqb[row] = f2bf(-(0.5f * s + 2.0f));
  short8 b;
  b[0] = (short)f2bf(v0.x); b[1] = (short)f2bf(v0.y);
  b[2] = (short)f2bf(v0.z); b[3] = (short)f2bf(v0.w);
  b[4] = (short)f2bf(v1.x); b[5] = (short)f2bf(v1.y);
  b[6] = (short)f2bf(v1.z); b[7] = (short)f2bf(v1.w);
  // chunk m covers k = m*8..m*8+7  ->  c = m>>1, half = m&1
  size_t dst = (size_t)(row >> 5) * 2048 + (size_t)(m >> 1) * 512
             + (size_t)((m & 1) * 32 + (row & 31)) * 8;
  *reinterpret_cast<short8*>(embF + dst) = b;
  if (tid < N) { pmax[tid] = 0u; pmin[tid] = 0xFFFFFFFFu; }
  if (tid == 0) out[0] = 0.f;
}

// Kernel 2: batch-hard mining, 32x32 tiles, fragment-ready coalesced loads.
// acc = dot - 0.5(sq_i+sq_j) - 4 = -(d/2+4) < 0 via 5th augmented MFMA; for
// all-negative floats u32 bits are monotone INCREASING in d, so
// key = (bits(acc)&~0x1FFF)|idx13 gives argmax(d)=u32max, argmin(d)=u32min.
// Combined globally with atomicMax/Min (jinv for max -> smaller j on ties).
__global__ __launch_bounds__(256, 4) void mine_kernel(
    const unsigned short* __restrict__ embF,
    const unsigned short* __restrict__ sqb, const int* __restrict__ cls,
    unsigned* __restrict__ pmax, unsigned* __restrict__ pmin) {
  const int lane = threadIdx.x & 63;
  const int wave = threadIdx.x >> 6;
  const int lo = lane & 31;
  const int half = lane >> 5;
  const int aT = blockIdx.x * 4 + wave;          // anchor tile 0..255
  const int rowBase = aT * 32;
  const int tBase = blockIdx.y * (256 / SPLITS);

  const short8* fr = reinterpret_cast<const short8*>(embF);
  // A fragments: chunk c at fr[tile*256 + c*64 + lane]  (coalesced)
  const short8* ea = fr + (size_t)aT * 256 + lane;
  short8 a0 = ea[0], a1 = ea[64], a2 = ea[128], a3 = ea[192];
  // Aug A frag: A'[m][0]=1.0, A'[m][1]=-(0.5*sq_m+2) (pre-encoded bf16).
  unsigned short sqm = sqb[rowBase + lo];
  const short one = (short)0x3F80;               // bf16 1.0
  short8 a4 = {(short)(half == 0 ? one : 0),
               (short)(half == 0 ? (short)sqm : 0), 0, 0, 0, 0, 0, 0};

  // C/D layout: col = lane&31, row = (reg&3) + 8*(reg>>2) + 4*half.
  int ci[16];
  #pragma unroll
  for (int r = 0; r < 16; ++r)
    ci[r] = cls[rowBase + (r & 3) + 8 * (r >> 2) + 4 * half];

  floatx16 zacc;
  #pragma unroll
  for (int i = 0; i < 16; ++i) zacc[i] = 0.f;

  unsigned maxk[16], mink[16];
  #pragma unroll
  for (int r = 0; r < 16; ++r) { maxk[r] = 0u; mink[r] = 0xFFFFFFFFu; }

  #pragma unroll 2
  for (int t = tBase; t < tBase + 256 / SPLITS; ++t) {
    const int cb = t * 32;
    const short8* eb = fr + (size_t)t * 256 + lane;
    short8 b0 = eb[0], b1 = eb[64], b2 = eb[128], b3 = eb[192];
    unsigned short sqn = sqb[cb + lo];
    int cj = cls[cb + lo];
    short8 b4 = {(short)(half == 0 ? (short)sqn : 0),
                 (short)(half == 0 ? one : 0), 0, 0, 0, 0, 0, 0};

    floatx16 acc = __builtin_amdgcn_mfma_f32_32x32x16_bf16(a0, b0, zacc, 0, 0, 0);
    acc = __builtin_amdgcn_mfma_f32_32x32x16_bf16(a1, b1, acc, 0, 0, 0);
    acc = __builtin_amdgcn_mfma_f32_32x32x16_bf16(a2, b2, acc, 0, 0, 0);
    acc = __builtin_amdgcn_mfma_f32_32x32x16_bf16(a3, b3, acc, 0, 0, 0);
    acc = __builtin_amdgcn_mfma_f32_32x32x16_bf16(a4, b4, acc, 0, 0, 0);

    const unsigned j = cb + lo;
    const unsigned jinv = 8191u - j;
    #pragma unroll
    for (int r = 0; r < 16; ++r) {
      unsigned kb = __float_as_uint(acc[r]) & 0xFFFFE000u;
      bool same = (ci[r] == cj);
      unsigned kp = same ? (kb | jinv) : 0u;
      unsigned kn = same ? 0xFFFFFFFFu : (kb | j);
      maxk[r] = maxk[r] > kp ? maxk[r] : kp;
      mink[r] = mink[r] < kn ? mink[r] : kn;
    }
  }

  // Column reduction within each 32-lane half (xor masks 1..16 stay in-half).
  #pragma unroll
  for (int off = 1; off < 32; off <<= 1) {
    #pragma unroll
    for (int r = 0; r < 16; ++r) {
      unsigned om = (unsigned)__shfl_xor((int)maxk[r], off);
      maxk[r] = maxk[r] > om ? maxk[r] : om;
      unsigned on = (unsigned)__shfl_xor((int)mink[r], off);
      mink[r] = mink[r] < on ? mink[r] : on;
    }
  }

  if (lo == 0) {
    #pragma unroll
    for (int r = 0; r < 16; ++r) {
      int row = rowBase + (r & 3) + 8 * (r >> 2) + 4 * half;
      atomicMax(&pmax[row], maxk[r]);
      atomicMin(&pmin[row], mink[r]);
    }
  }
}

// Kernel 3: decode winning indices, recompute ap/an in fp32 from ORIGINAL
// embeddings (matches reference), relu+margin, mean. 4 lanes per anchor.
__global__ __launch_bounds__(256) void finalize_kernel(
    const float* __restrict__ emb,
    const unsigned* __restrict__ pmax, const unsigned* __restrict__ pmin,
    float* __restrict__ out) {
  int tid = blockIdx.x * 256 + threadIdx.x;   // N*4 threads
  int anchor = tid >> 2;
  int part = tid & 3;
  int jp = 8191 - (int)(pmax[anchor] & 8191u);
  int jn = (int)(pmin[anchor] & 8191u);

  const float4* xi = reinterpret_cast<const float4*>(emb + (size_t)anchor * Dq) + part * 4;
  const float4* xp = reinterpret_cast<const float4*>(emb + (size_t)jp * Dq) + part * 4;
  const float4* xn = reinterpret_cast<const float4*>(emb + (size_t)jn * Dq) + part * 4;
  float ap = 0.f, an = 0.f;
  #pragma unroll
  for (int k = 0; k < 4; ++k) {
    float4 a = xi[k], p = xp[k], q = xn[k];
    float dx = a.x - p.x, dy = a.y - p.y, dz = a.z - p.z, dw = a.w - p.w;
    ap += dx * dx + dy * dy + dz * dz + dw * dw;
    dx = a.x - q.x; dy = a.y - q.y; dz = a.z - q.z; dw = a.w - q.w;
    an += dx * dx + dy * dy + dz * dz + dw * dw;
  }
  #pragma unroll
  for (int off = 1; off < 4; off <<= 1) {
    ap += __shfl_xor(ap, off);
    an += __shfl_xor(an, off);
  }
  float loss = (part == 0) ? fmaxf(ap - an + MARGIN, 0.f) : 0.f;
  #pragma unroll
  for (int off = 4; off < 64; off <<= 1) loss += __shfl_xor(loss, off);
  __shared__ float wsum[4];
  if ((threadIdx.x & 63) == 0) wsum[threadIdx.x >> 6] = loss;
  __syncthreads();
  if (threadIdx.x == 0)
    atomicAdd(out, (wsum[0] + wsum[1] + wsum[2] + wsum[3]) * (1.0f / (float)N));
}

extern "C" void kernel_launch(void* const* d_in, const int* in_sizes, int n_in,
                              void* d_out, int out_size, void* d_ws, size_t ws_size,
                              hipStream_t stream) {
  const float* emb = (const float*)d_in[0];
  const int* tgt = (const int*)d_in[1];   // int32 on device (verified R1-R3)
  float* out = (float*)d_out;

  char* ws = (char*)d_ws;
  unsigned short* embF = (unsigned short*)ws;                       // 1 MB tiled bf16
  unsigned short* sqb = (unsigned short*)(ws + (size_t)N * Dq * 2); // 16 KB
  unsigned* pmax = (unsigned*)(ws + (size_t)N * Dq * 2 + N * 2);    // 32 KB
  unsigned* pmin = pmax + N;                                        // 32 KB

  prep_kernel<<<N * 8 / 256, 256, 0, stream>>>(emb, embF, sqb, pmax, pmin, out);
  mine_kernel<<<dim3(N / 128, SPLITS), 256, 0, stream>>>(embF, sqb, tgt, pmax, pmin);
  finalize_kernel<<<N * 4 / 256, 256, 0, stream>>>(emb, pmax, pmin, out);
}